// Round 7
// baseline (6551.998 us; speedup 1.0000x reference)
//
#include <hip/hip_runtime.h>

#define NLAYER 6
#define NB     128     // batch
#define NT     512     // seq len
#define DIN    128     // layer-0 input size
#define NH     256     // hidden
#define NBLK   192     // 6 layers x 16 slices x 2 batch-groups, all co-resident
#define SLOT_U64 (NB*NH/4)            // ring slot in u64 units (4 bf16 each) = 8192
#define WF_BYTES  (6u*16u*4u*16u*64u*16u)   // 6.29 MB  pre-swizzled weights
#define XF_BYTES  (512u*2u*4u*4u*64u*16u)   // 16.78 MB pre-swizzled x

typedef __attribute__((ext_vector_type(8))) short short8;
typedef __attribute__((ext_vector_type(4))) float f32x4;
typedef __attribute__((ext_vector_type(4))) unsigned int u32x4;

__device__ __forceinline__ unsigned f2bf2(float lo, float hi){
  unsigned a = __float_as_uint(lo), b = __float_as_uint(hi);
  a = (a + 0x7fffu + ((a>>16)&1u)) >> 16;   // RNE bf16
  b = (b + 0x7fffu + ((b>>16)&1u)) >> 16;
  return a | (b<<16);
}
__device__ __forceinline__ unsigned long long f2bf4(float a, float b, float c, float d){
  return (unsigned long long)f2bf2(a,b) | ((unsigned long long)f2bf2(c,d) << 32);
}
__device__ __forceinline__ short8 pack16(unsigned long long lo, unsigned long long hi){
  union { unsigned long long u[2]; short8 v; } w; w.u[0]=lo; w.u[1]=hi; return w.v;
}
__device__ __forceinline__ short8 frag_of(u32x4 v){
  union { u32x4 u; short8 s; } w; w.u = v; return w.s;
}
__device__ __forceinline__ short8 ld8f_frag(const float* p){
  f32x4 a = *(const f32x4*)p;
  f32x4 b = *(const f32x4*)(p+4);
  return pack16(f2bf4(a[0],a[1],a[2],a[3]), f2bf4(b[0],b[1],b[2],b[3]));
}

__device__ __forceinline__ float sigmf(float v){ return 1.0f/(1.0f + __expf(-v)); }
__device__ __forceinline__ float tanhfast(float v){
  v = fminf(fmaxf(v, -15.0f), 15.0f);
  float e = __expf(2.0f*v);
  return (e - 1.0f)/(e + 1.0f);
}

__device__ __forceinline__ int ld_flag(int* p){
  return __hip_atomic_load(p, __ATOMIC_RELAXED, __HIP_MEMORY_SCOPE_AGENT);
}
__device__ __forceinline__ void st_flag(int* p, int v){
  __hip_atomic_store(p, v, __ATOMIC_RELAXED, __HIP_MEMORY_SCOPE_AGENT);
}
__device__ __forceinline__ void ring_st(unsigned long long* p, unsigned long long v){
  __hip_atomic_store(p, v, __ATOMIC_RELAXED, __HIP_MEMORY_SCOPE_AGENT);
}
__device__ __forceinline__ void poll_ge16(int* tp, int val, int lane){
  int guard = 0;
  for (;;){
    int v = (lane < 16) ? ld_flag(tp + lane) : 0x7fffffff;
    if (__ballot(v >= val) == ~0ull) break;
    __builtin_amdgcn_s_sleep(1);
    if (++guard > (1<<22)) break;   // failsafe only
  }
}
// combined poll: lanes 0..15 check prev tags >= thrPrev, lanes 16..31 own tags >= thrOwn.
// pass thr = INT_MIN to disable a side.
__device__ __forceinline__ void poll2(int* prevp, int thrPrev, int* ownp, int thrOwn, int lane){
  int* p  = (lane < 16) ? (prevp + lane) : (ownp + (lane & 15));
  int thr = (lane < 16) ? thrPrev : thrOwn;
  int guard = 0;
  for (;;){
    int v = (lane < 32) ? ld_flag(p) : 0x7fffffff;
    if (__ballot(v >= thr) == ~0ull) break;
    __builtin_amdgcn_s_sleep(1);
    if (++guard > (1<<22)) break;   // failsafe only
  }
}

// ---- self-contained batched sc1 loads: issue + wait INSIDE one asm block.
// All outputs early-clobber => disjoint from address regs; on exit data is ready.
__device__ __forceinline__ void ld16_sync(const unsigned long long* pa,
                                          const unsigned long long* pb, u32x4 r[16]){
  asm volatile(
    "global_load_dwordx4 %0, %16, off sc1\n\t"
    "global_load_dwordx4 %1, %16, off offset:64 sc1\n\t"
    "global_load_dwordx4 %2, %16, off offset:128 sc1\n\t"
    "global_load_dwordx4 %3, %16, off offset:192 sc1\n\t"
    "global_load_dwordx4 %4, %16, off offset:256 sc1\n\t"
    "global_load_dwordx4 %5, %16, off offset:320 sc1\n\t"
    "global_load_dwordx4 %6, %16, off offset:384 sc1\n\t"
    "global_load_dwordx4 %7, %16, off offset:448 sc1\n\t"
    "global_load_dwordx4 %8, %17, off sc1\n\t"
    "global_load_dwordx4 %9, %17, off offset:64 sc1\n\t"
    "global_load_dwordx4 %10, %17, off offset:128 sc1\n\t"
    "global_load_dwordx4 %11, %17, off offset:192 sc1\n\t"
    "global_load_dwordx4 %12, %17, off offset:256 sc1\n\t"
    "global_load_dwordx4 %13, %17, off offset:320 sc1\n\t"
    "global_load_dwordx4 %14, %17, off offset:384 sc1\n\t"
    "global_load_dwordx4 %15, %17, off offset:448 sc1\n\t"
    "s_waitcnt vmcnt(0)"
    : "=&v"(r[0]),"=&v"(r[1]),"=&v"(r[2]),"=&v"(r[3]),
      "=&v"(r[4]),"=&v"(r[5]),"=&v"(r[6]),"=&v"(r[7]),
      "=&v"(r[8]),"=&v"(r[9]),"=&v"(r[10]),"=&v"(r[11]),
      "=&v"(r[12]),"=&v"(r[13]),"=&v"(r[14]),"=&v"(r[15])
    : "v"(pa), "v"(pb)
    : "memory");
}
__device__ __forceinline__ void ld8_sync(const unsigned long long* pa, u32x4 r[8]){
  asm volatile(
    "global_load_dwordx4 %0, %8, off sc1\n\t"
    "global_load_dwordx4 %1, %8, off offset:64 sc1\n\t"
    "global_load_dwordx4 %2, %8, off offset:128 sc1\n\t"
    "global_load_dwordx4 %3, %8, off offset:192 sc1\n\t"
    "global_load_dwordx4 %4, %8, off offset:256 sc1\n\t"
    "global_load_dwordx4 %5, %8, off offset:320 sc1\n\t"
    "global_load_dwordx4 %6, %8, off offset:384 sc1\n\t"
    "global_load_dwordx4 %7, %8, off offset:448 sc1\n\t"
    "s_waitcnt vmcnt(0)"
    : "=&v"(r[0]),"=&v"(r[1]),"=&v"(r[2]),"=&v"(r[3]),
      "=&v"(r[4]),"=&v"(r[5]),"=&v"(r[6]),"=&v"(r[7])
    : "v"(pa)
    : "memory");
}

// ---------------- prep kernels: one-time swizzle/convert into workspace ----------------
__global__ void prep_w(const float* __restrict__ wih0, const float* __restrict__ wih,
                       const float* __restrict__ whh, unsigned char* __restrict__ wf)
{
  int idx = blockIdx.x*256 + threadIdx.x;          // 6*16*4*16*64 = 393216
  int lane = idx & 63;
  int kt   = (idx >> 6) & 15;
  int q    = (idx >> 10) & 3;
  int s    = (idx >> 12) & 15;
  int l    = idx >> 16;
  if (l >= NLAYER) return;
  const int KX = (l == 0) ? DIN : NH;
  if (kt*32 >= KX + NH) return;                     // l==0: kt 12..15 unused
  int k0  = kt*32 + (lane >> 4)*8;
  int row = q*NH + s*16 + (lane & 15);
  const float* src;
  if (k0 < KX){
    src = (l == 0) ? (wih0 + (size_t)row*DIN + k0)
                   : (wih + (size_t)(l-1)*(4*NH*NH) + (size_t)row*NH + k0);
  } else {
    src = whh + (size_t)l*(4*NH*NH) + (size_t)row*NH + (k0 - KX);
  }
  f32x4 a = *(const f32x4*)src;
  f32x4 b = *(const f32x4*)(src+4);
  ulonglong2 v;
  v.x = f2bf4(a[0],a[1],a[2],a[3]);
  v.y = f2bf4(b[0],b[1],b[2],b[3]);
  *(ulonglong2*)(wf + (size_t)idx*16) = v;
}

__global__ void prep_x(const float* __restrict__ x, unsigned char* __restrict__ xf)
{
  int idx = blockIdx.x*256 + threadIdx.x;          // 512*2*4*4*64 = 1048576
  int lane = idx & 63;
  int kt   = (idx >> 6) & 3;
  int wv   = (idx >> 8) & 3;
  int g    = (idx >> 10) & 1;
  int t    = idx >> 11;
  int b    = g*64 + wv*16 + (lane & 15);
  int k    = kt*32 + (lane >> 4)*8;
  const float* src = x + ((size_t)b*NT + t)*DIN + k;
  f32x4 a = *(const f32x4*)src;
  f32x4 c = *(const f32x4*)(src+4);
  ulonglong2 v;
  v.x = f2bf4(a[0],a[1],a[2],a[3]);
  v.y = f2bf4(c[0],c[1],c[2],c[3]);
  *(ulonglong2*)(xf + (size_t)idx*16) = v;
}

// ---------------- main: wave-dataflow LSTM ----------------
template<int NKX, int KIT>
__device__ __forceinline__ void lstm_run(
    const unsigned char* __restrict__ wf,   // this (l,s) weight frags
    const unsigned char* __restrict__ xf,   // x frags (l==0 only)
    const float* __restrict__ h0, const float* __restrict__ c0,
    const float* __restrict__ bi, const float* __restrict__ bh,
    float* __restrict__ out,
    int* __restrict__ tags, int* __restrict__ acks,
    unsigned long long* __restrict__ ring,
    int Wv, int l, int s, int g, int wv, int lane)
{
  constexpr int NKH = KIT - NKX;         // 8
  const int l15  = lane & 15;
  const int quad = lane >> 4;
  const int bloc = g*64 + wv*16 + l15;
  const int jcol = s*16 + quad*4;
  const int Wm   = Wv - 1;

  f32x4 bsv[4];
  #pragma unroll
  for (int q = 0; q < 4; ++q){
    f32x4 a = *(const f32x4*)(bi + q*NH + jcol);
    f32x4 b = *(const f32x4*)(bh + q*NH + jcol);
    bsv[q] = a + b;
  }
  float cc[4];
  {
    f32x4 cv = *(const f32x4*)(c0 + ((size_t)l*NB + bloc)*NH + jcol);
    cc[0]=cv[0]; cc[1]=cv[1]; cc[2]=cv[2]; cc[3]=cv[3];
  }

  int* tagOwn  = tags + ((l*2 + g)*Wv)*64;                 // [slot][wv][s]
  int* tagPrev = tags + (((l > 0 ? l-1 : 0)*2 + g)*Wv)*64;
  int* ackOwn  = acks + ((l*2 + g)*Wv)*64;
  int* ackPrev = acks + (((l > 0 ? l-1 : 0)*2 + g)*Wv)*64;
  const unsigned long long* ringPrev = ring + (size_t)(l > 0 ? l-1 : 0)*Wv*SLOT_U64;
  unsigned long long*       ringOwn  = ring + (size_t)l*Wv*SLOT_U64;
  const bool lastL = (l == NLAYER-1);
  const bool bp    = (Wv < NT);

  for (int t = 0; t < NT; ++t){
    const int slot  = t & Wm;
    const int pslot = (t-1) & Wm;

    if (bp && !lastL && t >= Wv) poll_ge16(ackOwn + slot*64 + wv*16, t - Wv + 1, lane);

    // ---- single combined poll: prev-layer tags (>= t+1) and own tags (>= t) ----
    {
      int thrP = (NKX == 8) ? (t+1) : (int)0x80000000;
      int thrO = (t > 0)    ? t     : (int)0x80000000;
      poll2(tagPrev + slot*64 + wv*16, thrP, tagOwn + pslot*64 + wv*16, thrO, lane);
    }

    // ---- B fragments ----
    short8 Bf[KIT];
    if constexpr (NKX == 4){
      const unsigned char* px = xf + ((size_t)((t*2 + g)*4 + wv))*4096 + lane*16;
      #pragma unroll
      for (int k = 0; k < 4; ++k){
        ulonglong2 v = *(const ulonglong2*)(px + k*1024);
        Bf[k] = pack16(v.x, v.y);
      }
      if (t == 0){
        const float* ph = h0 + ((size_t)l*NB + bloc)*NH + quad*8;
        #pragma unroll
        for (int k = 0; k < NKH; ++k) Bf[NKX+k] = ld8f_frag(ph + k*32);
      } else {
        u32x4 hb[8];
        ld8_sync(ringOwn + (size_t)pslot*SLOT_U64 + (size_t)bloc*64 + quad*2, hb);
        #pragma unroll
        for (int k = 0; k < NKH; ++k) Bf[NKX+k] = frag_of(hb[k]);
      }
    } else {
      if (t == 0){
        u32x4 xb[8];
        ld8_sync(ringPrev + (size_t)slot*SLOT_U64 + (size_t)bloc*64 + quad*2, xb);
        #pragma unroll
        for (int k = 0; k < 8; ++k) Bf[k] = frag_of(xb[k]);
        const float* ph = h0 + ((size_t)l*NB + bloc)*NH + quad*8;
        #pragma unroll
        for (int k = 0; k < NKH; ++k) Bf[NKX+k] = ld8f_frag(ph + k*32);
      } else {
        u32x4 rb[16];
        ld16_sync(ringPrev + (size_t)slot*SLOT_U64 + (size_t)bloc*64 + quad*2,
                  ringOwn  + (size_t)pslot*SLOT_U64 + (size_t)bloc*64 + quad*2, rb);
        #pragma unroll
        for (int k = 0; k < 16; ++k) Bf[k] = frag_of(rb[k]);
      }
    }

    // ---- MFMAs (weights streamed from L1/L2-cached wf) ----
    f32x4 a0 = {0,0,0,0}, a1 = {0,0,0,0}, a2 = {0,0,0,0}, a3 = {0,0,0,0};
    #pragma unroll
    for (int k = 0; k < KIT; ++k){
      const unsigned char* ap = wf + ((size_t)k*64 + lane)*16;
      a0 = __builtin_amdgcn_mfma_f32_16x16x32_bf16(frag_of(*(const u32x4*)(ap + 0*16*1024)), Bf[k], a0, 0, 0, 0);
      a1 = __builtin_amdgcn_mfma_f32_16x16x32_bf16(frag_of(*(const u32x4*)(ap + 1*16*1024)), Bf[k], a1, 0, 0, 0);
      a2 = __builtin_amdgcn_mfma_f32_16x16x32_bf16(frag_of(*(const u32x4*)(ap + 2*16*1024)), Bf[k], a2, 0, 0, 0);
      a3 = __builtin_amdgcn_mfma_f32_16x16x32_bf16(frag_of(*(const u32x4*)(ap + 3*16*1024)), Bf[k], a3, 0, 0, 0);
    }
    if (bp){
      if (NKX == 8 && lane == 0) st_flag(ackPrev + slot*64 + wv*16 + s, t+1);
    }

    // ---- fused gate nonlinearities + state update ----
    float hv[4];
    #pragma unroll
    for (int r = 0; r < 4; ++r){
      float ig = sigmf(a0[r] + bsv[0][r]);
      float fg = sigmf(a1[r] + bsv[1][r]);
      float gv = tanhfast(a2[r] + bsv[2][r]);
      float og = sigmf(a3[r] + bsv[3][r]);
      float cn = fg*cc[r] + ig*gv;
      cc[r] = cn;
      hv[r] = og * tanhfast(cn);
    }

    // ---- publish: 8B device-coherent store, drain, per-wave tag ----
    ring_st(ringOwn + (size_t)slot*SLOT_U64 + (size_t)bloc*64 + s*4 + quad,
            f2bf4(hv[0], hv[1], hv[2], hv[3]));
    if (t == NT-1){
      f32x4 ov; ov[0]=hv[0]; ov[1]=hv[1]; ov[2]=hv[2]; ov[3]=hv[3];
      *(f32x4*)(out + ((size_t)l*NB + bloc)*NH + jcol) = ov;
    }
    asm volatile("s_waitcnt vmcnt(0)" ::: "memory");
    if (lane == 0) st_flag(tagOwn + slot*64 + wv*16 + s, t+1);
  }
}

__global__ __launch_bounds__(256, 1)
void lstm_pipe(const unsigned char* __restrict__ wf, const unsigned char* __restrict__ xf,
               const float* __restrict__ h0,  const float* __restrict__ c0,
               const float* __restrict__ bih, const float* __restrict__ bhh,
               float* __restrict__ out, int* __restrict__ tags, int* __restrict__ acks,
               unsigned long long* __restrict__ ring, int Wv)
{
  const int tid  = threadIdx.x;
  const int bid  = blockIdx.x;
  const int l    = bid >> 5;          // 32 blocks per layer
  const int s    = (bid >> 1) & 15;
  const int g    = bid & 1;
  const int lane = tid & 63;
  const int wv   = tid >> 6;

  const unsigned char* wfl = wf + (size_t)(l*16 + s)*65536;
  if (l == 0)
    lstm_run<4,12>(wfl, xf, h0, c0, bih, bhh,
                   out, tags, acks, ring, Wv, 0, s, g, wv, lane);
  else
    lstm_run<8,16>(wfl, xf, h0, c0,
                   bih + (size_t)l*(4*NH), bhh + (size_t)l*(4*NH),
                   out, tags, acks, ring, Wv, l, s, g, wv, lane);
}

extern "C" void kernel_launch(void* const* d_in, const int* in_sizes, int n_in,
                              void* d_out, int out_size, void* d_ws, size_t ws_size,
                              hipStream_t stream)
{
  (void)in_sizes; (void)n_in; (void)out_size;
  const float* x    = (const float*)d_in[0];
  const float* h0   = (const float*)d_in[1];
  const float* c0   = (const float*)d_in[2];
  const float* wih0 = (const float*)d_in[3];
  const float* wih  = (const float*)d_in[4];
  const float* whh  = (const float*)d_in[5];
  const float* bih  = (const float*)d_in[6];
  const float* bhh  = (const float*)d_in[7];

  // full-depth ring preferred; shrink if ws small (activates WAR/ack machinery)
  int Wv = NT;
  size_t tagB;
  for (;;){
    tagB = (size_t)NLAYER*2*Wv*64*4;
    size_t ringB = (size_t)NLAYER*Wv*SLOT_U64*8;
    if (2*tagB + WF_BYTES + XF_BYTES + ringB <= ws_size || Wv <= 4) break;
    Wv >>= 1;
  }

  char* p = (char*)d_ws;
  int* tags = (int*)p;                 p += tagB;
  int* acks = (int*)p;                 p += tagB;
  unsigned char* wf = (unsigned char*)p; p += WF_BYTES;
  unsigned char* xf = (unsigned char*)p; p += XF_BYTES;
  unsigned long long* ring = (unsigned long long*)p;

  (void)hipMemsetAsync(d_ws, 0, 2*tagB, stream);
  hipLaunchKernelGGL(prep_w, dim3(1536), dim3(256), 0, stream, wih0, wih, whh, wf);
  hipLaunchKernelGGL(prep_x, dim3(4096), dim3(256), 0, stream, x, xf);
  hipLaunchKernelGGL(lstm_pipe, dim3(NBLK), dim3(256), 0, stream,
                     wf, xf, h0, c0, bih, bhh,
                     (float*)d_out, tags, acks, ring, Wv);
}

// Round 8
// 6445.585 us; speedup vs baseline: 1.0165x; 1.0165x over previous
//
#include <hip/hip_runtime.h>

#define NLAYER 6
#define NB     128     // batch
#define NT     512     // seq len
#define DIN    128     // layer-0 input size
#define NH     256     // hidden
#define NBLK   192     // 6 layers x 16 slices x 2 batch-groups, all co-resident
#define WV     64      // ring depth (slots); 49 MB total -> L3-resident
#define ACKM   32      // ack poll margin (steps)
#define SLOTB  65536   // bytes per (l,slot,g): 64 rows x 1 KB
#define WF_BYTES  (6u*16u*4u*16u*64u*16u)   // 6.29 MB  pre-swizzled weights
#define XF_BYTES  (512u*2u*4u*4u*64u*16u)   // 16.78 MB pre-swizzled x
#define ACK_INTS  (NLAYER*2*64)             // [l][g][s*4+wv]

typedef __attribute__((ext_vector_type(8))) short short8;
typedef __attribute__((ext_vector_type(4))) float f32x4;
typedef __attribute__((ext_vector_type(4))) unsigned int u32x4;

__device__ __forceinline__ unsigned f2bf2(float lo, float hi){
  unsigned a = __float_as_uint(lo), b = __float_as_uint(hi);
  a = (a + 0x7fffu + ((a>>16)&1u)) >> 16;   // RNE bf16
  b = (b + 0x7fffu + ((b>>16)&1u)) >> 16;
  return a | (b<<16);
}
__device__ __forceinline__ unsigned long long f2bf4(float a, float b, float c, float d){
  return (unsigned long long)f2bf2(a,b) | ((unsigned long long)f2bf2(c,d) << 32);
}
__device__ __forceinline__ short8 pack16(unsigned long long lo, unsigned long long hi){
  union { unsigned long long u[2]; short8 v; } w; w.u[0]=lo; w.u[1]=hi; return w.v;
}
__device__ __forceinline__ short8 frag2(u32x4 a, u32x4 b){   // two 8B payloads -> frag
  union { unsigned u[4]; short8 s; } w;
  w.u[0]=a.x; w.u[1]=a.y; w.u[2]=b.x; w.u[3]=b.y; return w.s;
}
__device__ __forceinline__ short8 frag_of(u32x4 v){
  union { u32x4 u; short8 s; } w; w.u = v; return w.s;
}
__device__ __forceinline__ short8 ld8f_frag(const float* p){
  f32x4 a = *(const f32x4*)p;
  f32x4 b = *(const f32x4*)(p+4);
  return pack16(f2bf4(a[0],a[1],a[2],a[3]), f2bf4(b[0],b[1],b[2],b[3]));
}

__device__ __forceinline__ float sigmf(float v){ return 1.0f/(1.0f + __expf(-v)); }
__device__ __forceinline__ float tanhfast(float v){
  v = fminf(fmaxf(v, -15.0f), 15.0f);
  float e = __expf(2.0f*v);
  return (e - 1.0f)/(e + 1.0f);
}

__device__ __forceinline__ int ld_flag(int* p){
  return __hip_atomic_load(p, __ATOMIC_RELAXED, __HIP_MEMORY_SCOPE_AGENT);
}
__device__ __forceinline__ void st_flag(int* p, int v){
  __hip_atomic_store(p, v, __ATOMIC_RELAXED, __HIP_MEMORY_SCOPE_AGENT);
}

// producer publish: 8B h payload + 4B epoch in ONE 16B device-coherent store.
__device__ __forceinline__ void pub16(unsigned char* p, unsigned lo, unsigned hi, int epoch){
  u32x4 v; v.x = lo; v.y = hi; v.z = (unsigned)epoch; v.w = 0u;
  asm volatile("global_store_dwordx4 %0, %1, off sc1" :: "v"(p), "v"(v) : "memory");
}

// 16 epoch-stamped chunk loads (one ring row region), issue+wait in one block.
// chunk pairs at kt*128 + {0,16}, kt=0..7; base includes row + quad*32.
#define LD16_BODY(P) \
    "global_load_dwordx4 %0, " P ", off sc1\n\t" \
    "global_load_dwordx4 %1, " P ", off offset:16 sc1\n\t" \
    "global_load_dwordx4 %2, " P ", off offset:128 sc1\n\t" \
    "global_load_dwordx4 %3, " P ", off offset:144 sc1\n\t" \
    "global_load_dwordx4 %4, " P ", off offset:256 sc1\n\t" \
    "global_load_dwordx4 %5, " P ", off offset:272 sc1\n\t" \
    "global_load_dwordx4 %6, " P ", off offset:384 sc1\n\t" \
    "global_load_dwordx4 %7, " P ", off offset:400 sc1\n\t" \
    "global_load_dwordx4 %8, " P ", off offset:512 sc1\n\t" \
    "global_load_dwordx4 %9, " P ", off offset:528 sc1\n\t" \
    "global_load_dwordx4 %10, " P ", off offset:640 sc1\n\t" \
    "global_load_dwordx4 %11, " P ", off offset:656 sc1\n\t" \
    "global_load_dwordx4 %12, " P ", off offset:768 sc1\n\t" \
    "global_load_dwordx4 %13, " P ", off offset:784 sc1\n\t" \
    "global_load_dwordx4 %14, " P ", off offset:896 sc1\n\t" \
    "global_load_dwordx4 %15, " P ", off offset:912 sc1\n\t"

__device__ __forceinline__ void ld16_once(const unsigned char* pa, u32x4 r[16]){
  asm volatile(
    LD16_BODY("%16")
    "s_waitcnt vmcnt(0)"
    : "=&v"(r[0]),"=&v"(r[1]),"=&v"(r[2]),"=&v"(r[3]),
      "=&v"(r[4]),"=&v"(r[5]),"=&v"(r[6]),"=&v"(r[7]),
      "=&v"(r[8]),"=&v"(r[9]),"=&v"(r[10]),"=&v"(r[11]),
      "=&v"(r[12]),"=&v"(r[13]),"=&v"(r[14]),"=&v"(r[15])
    : "v"(pa)
    : "memory");
}

// retry until all 16 chunk epochs match
__device__ __forceinline__ void ld16_epoch(const unsigned char* pa, int epoch, u32x4 r[16]){
  int guard = 0;
  for (;;){
    ld16_once(pa, r);
    bool ok = true;
    #pragma unroll
    for (int i = 0; i < 16; ++i) ok &= (r[i].z == (unsigned)epoch);
    if (__ballot(ok) == ~0ull) break;
    __builtin_amdgcn_s_sleep(1);
    if (++guard > (1<<18)) break;   // failsafe only
  }
}

// fused x(prev ring)+h(own ring) retry: 32 chunks, one vmcnt, two epochs
__device__ __forceinline__ void ld32_epoch(const unsigned char* pa, int ea,
                                           const unsigned char* pb, int eb,
                                           u32x4 rx[16], u32x4 rh[16]){
  int guard = 0;
  for (;;){
    asm volatile(
      LD16_BODY("%32")
      "global_load_dwordx4 %16, %33, off sc1\n\t"
      "global_load_dwordx4 %17, %33, off offset:16 sc1\n\t"
      "global_load_dwordx4 %18, %33, off offset:128 sc1\n\t"
      "global_load_dwordx4 %19, %33, off offset:144 sc1\n\t"
      "global_load_dwordx4 %20, %33, off offset:256 sc1\n\t"
      "global_load_dwordx4 %21, %33, off offset:272 sc1\n\t"
      "global_load_dwordx4 %22, %33, off offset:384 sc1\n\t"
      "global_load_dwordx4 %23, %33, off offset:400 sc1\n\t"
      "global_load_dwordx4 %24, %33, off offset:512 sc1\n\t"
      "global_load_dwordx4 %25, %33, off offset:528 sc1\n\t"
      "global_load_dwordx4 %26, %33, off offset:640 sc1\n\t"
      "global_load_dwordx4 %27, %33, off offset:656 sc1\n\t"
      "global_load_dwordx4 %28, %33, off offset:768 sc1\n\t"
      "global_load_dwordx4 %29, %33, off offset:784 sc1\n\t"
      "global_load_dwordx4 %30, %33, off offset:896 sc1\n\t"
      "global_load_dwordx4 %31, %33, off offset:912 sc1\n\t"
      "s_waitcnt vmcnt(0)"
      : "=&v"(rx[0]),"=&v"(rx[1]),"=&v"(rx[2]),"=&v"(rx[3]),
        "=&v"(rx[4]),"=&v"(rx[5]),"=&v"(rx[6]),"=&v"(rx[7]),
        "=&v"(rx[8]),"=&v"(rx[9]),"=&v"(rx[10]),"=&v"(rx[11]),
        "=&v"(rx[12]),"=&v"(rx[13]),"=&v"(rx[14]),"=&v"(rx[15]),
        "=&v"(rh[0]),"=&v"(rh[1]),"=&v"(rh[2]),"=&v"(rh[3]),
        "=&v"(rh[4]),"=&v"(rh[5]),"=&v"(rh[6]),"=&v"(rh[7]),
        "=&v"(rh[8]),"=&v"(rh[9]),"=&v"(rh[10]),"=&v"(rh[11]),
        "=&v"(rh[12]),"=&v"(rh[13]),"=&v"(rh[14]),"=&v"(rh[15])
      : "v"(pa), "v"(pb)
      : "memory");
    bool ok = true;
    #pragma unroll
    for (int i = 0; i < 16; ++i) ok &= (rx[i].z == (unsigned)ea);
    #pragma unroll
    for (int i = 0; i < 16; ++i) ok &= (rh[i].z == (unsigned)eb);
    if (__ballot(ok) == ~0ull) break;
    __builtin_amdgcn_s_sleep(1);
    if (++guard > (1<<18)) break;   // failsafe only
  }
}

// all-64 ack poll (one 4B load per lane per retry)
__device__ __forceinline__ void poll_ack(int* ap, int thr, int lane){
  int guard = 0;
  for (;;){
    int v = ld_flag(ap + lane);
    if (__ballot(v >= thr) == ~0ull) break;
    __builtin_amdgcn_s_sleep(4);
    if (++guard > (1<<18)) break;   // failsafe only
  }
}

// ---------------- prep kernels: one-time swizzle/convert into workspace ----------------
__global__ void prep_w(const float* __restrict__ wih0, const float* __restrict__ wih,
                       const float* __restrict__ whh, unsigned char* __restrict__ wf)
{
  int idx = blockIdx.x*256 + threadIdx.x;          // 6*16*4*16*64 = 393216
  int lane = idx & 63;
  int kt   = (idx >> 6) & 15;
  int q    = (idx >> 10) & 3;
  int s    = (idx >> 12) & 15;
  int l    = idx >> 16;
  if (l >= NLAYER) return;
  const int KX = (l == 0) ? DIN : NH;
  if (kt*32 >= KX + NH) return;                     // l==0: kt 12..15 unused
  int k0  = kt*32 + (lane >> 4)*8;
  int row = q*NH + s*16 + (lane & 15);
  const float* src;
  if (k0 < KX){
    src = (l == 0) ? (wih0 + (size_t)row*DIN + k0)
                   : (wih + (size_t)(l-1)*(4*NH*NH) + (size_t)row*NH + k0);
  } else {
    src = whh + (size_t)l*(4*NH*NH) + (size_t)row*NH + (k0 - KX);
  }
  f32x4 a = *(const f32x4*)src;
  f32x4 b = *(const f32x4*)(src+4);
  ulonglong2 v;
  v.x = f2bf4(a[0],a[1],a[2],a[3]);
  v.y = f2bf4(b[0],b[1],b[2],b[3]);
  *(ulonglong2*)(wf + (size_t)idx*16) = v;
}

__global__ void prep_x(const float* __restrict__ x, unsigned char* __restrict__ xf)
{
  int idx = blockIdx.x*256 + threadIdx.x;          // 512*2*4*4*64 = 1048576
  int lane = idx & 63;
  int kt   = (idx >> 6) & 3;
  int wv   = (idx >> 8) & 3;
  int g    = (idx >> 10) & 1;
  int t    = idx >> 11;
  int b    = g*64 + wv*16 + (lane & 15);
  int k    = kt*32 + (lane >> 4)*8;
  const float* src = x + ((size_t)b*NT + t)*DIN + k;
  f32x4 a = *(const f32x4*)src;
  f32x4 c = *(const f32x4*)(src+4);
  ulonglong2 v;
  v.x = f2bf4(a[0],a[1],a[2],a[3]);
  v.y = f2bf4(c[0],c[1],c[2],c[3]);
  *(ulonglong2*)(xf + (size_t)idx*16) = v;
}

// ---------------- main: wave-dataflow LSTM, epoch-stamped single-RT exchange ----------------
template<int NKX, int KIT>
__device__ __forceinline__ void lstm_run(
    const unsigned char* __restrict__ wf,   // this (l,s) weight frags
    const unsigned char* __restrict__ xf,   // x frags (l==0 only)
    const float* __restrict__ h0, const float* __restrict__ c0,
    const float* __restrict__ bi, const float* __restrict__ bh,
    float* __restrict__ out, int* __restrict__ acks,
    unsigned char* __restrict__ ring,
    int l, int s, int g, int wv, int lane)
{
  constexpr int NKH = KIT - NKX;         // 8
  const int l15  = lane & 15;
  const int quad = lane >> 4;
  const int bloc = g*64 + wv*16 + l15;
  const int jcol = s*16 + quad*4;

  f32x4 bsv[4];
  #pragma unroll
  for (int q = 0; q < 4; ++q){
    f32x4 a = *(const f32x4*)(bi + q*NH + jcol);
    f32x4 b = *(const f32x4*)(bh + q*NH + jcol);
    bsv[q] = a + b;
  }
  float cc[4];
  {
    f32x4 cv = *(const f32x4*)(c0 + ((size_t)l*NB + bloc)*NH + jcol);
    cc[0]=cv[0]; cc[1]=cv[1]; cc[2]=cv[2]; cc[3]=cv[3];
  }

  // ring bases: slot (l, t&Wm, g), row = wv*16+l15 (1KB/row)
  const int rowoff  = (wv*16 + l15)*1024 + quad*32;   // consumer base within slot
  unsigned char* ringOwnL  = ring + (size_t)(l*2 + g)*WV*SLOTB;
  unsigned char* ringPrevL = ring + (size_t)((l > 0 ? l-1 : 0)*2 + g)*WV*SLOTB;
  int* ackNext = acks + ((l < NLAYER-1 ? l+1 : l)*2 + g)*64;
  int* ackOwn  = acks + (l*2 + g)*64 + (s*4 + wv);
  const bool lastL = (l == NLAYER-1);
  int ackSafe = WV - 1;

  // producer address offset within slot
  const int prodoff = (wv*16 + l15)*1024 + (s*4 + quad)*16;

  for (int t = 0; t < NT; ++t){
    const int slot  = t & (WV-1);
    const int pslot = (t-1) & (WV-1);

    // lazy WAR throttle: ensure next layer consumed slot being overwritten
    if (!lastL && t > ackSafe){
      poll_ack(ackNext, t - WV + ACKM, lane);
      ackSafe = t + ACKM;
    }

    // ---- acquire B fragments (single fused RT) ----
    short8 Bf[KIT];
    if constexpr (NKX == 4){
      const unsigned char* px = xf + ((size_t)((t*2 + g)*4 + wv))*4096 + lane*16;
      #pragma unroll
      for (int k = 0; k < 4; ++k){
        ulonglong2 v = *(const ulonglong2*)(px + k*1024);
        Bf[k] = pack16(v.x, v.y);
      }
      if (t == 0){
        const float* ph = h0 + ((size_t)l*NB + bloc)*NH + quad*8;
        #pragma unroll
        for (int k = 0; k < NKH; ++k) Bf[NKX+k] = ld8f_frag(ph + k*32);
      } else {
        u32x4 rh[16];
        ld16_epoch(ringOwnL + (size_t)pslot*SLOTB + rowoff, t, rh);
        #pragma unroll
        for (int k = 0; k < NKH; ++k) Bf[NKX+k] = frag2(rh[2*k], rh[2*k+1]);
      }
    } else {
      if (t == 0){
        u32x4 rx[16];
        ld16_epoch(ringPrevL + (size_t)slot*SLOTB + rowoff, 1, rx);
        #pragma unroll
        for (int k = 0; k < 8; ++k) Bf[k] = frag2(rx[2*k], rx[2*k+1]);
        const float* ph = h0 + ((size_t)l*NB + bloc)*NH + quad*8;
        #pragma unroll
        for (int k = 0; k < NKH; ++k) Bf[NKX+k] = ld8f_frag(ph + k*32);
      } else {
        u32x4 rx[16], rh[16];
        ld32_epoch(ringPrevL + (size_t)slot*SLOTB + rowoff, t+1,
                   ringOwnL  + (size_t)pslot*SLOTB + rowoff, t, rx, rh);
        #pragma unroll
        for (int k = 0; k < 8; ++k) Bf[k]   = frag2(rx[2*k], rx[2*k+1]);
        #pragma unroll
        for (int k = 0; k < 8; ++k) Bf[8+k] = frag2(rh[2*k], rh[2*k+1]);
      }
      // ack: x reads of slot t complete (loads retired before this store issues)
      if (lane == 0) st_flag(ackOwn, t);
    }

    // ---- MFMAs (weights streamed from L2-cached wf) ----
    f32x4 a0 = {0,0,0,0}, a1 = {0,0,0,0}, a2 = {0,0,0,0}, a3 = {0,0,0,0};
    #pragma unroll
    for (int k = 0; k < KIT; ++k){
      const unsigned char* ap = wf + ((size_t)k*64 + lane)*16;
      a0 = __builtin_amdgcn_mfma_f32_16x16x32_bf16(frag_of(*(const u32x4*)(ap + 0*16*1024)), Bf[k], a0, 0, 0, 0);
      a1 = __builtin_amdgcn_mfma_f32_16x16x32_bf16(frag_of(*(const u32x4*)(ap + 1*16*1024)), Bf[k], a1, 0, 0, 0);
      a2 = __builtin_amdgcn_mfma_f32_16x16x32_bf16(frag_of(*(const u32x4*)(ap + 2*16*1024)), Bf[k], a2, 0, 0, 0);
      a3 = __builtin_amdgcn_mfma_f32_16x16x32_bf16(frag_of(*(const u32x4*)(ap + 3*16*1024)), Bf[k], a3, 0, 0, 0);
    }

    // ---- fused gate nonlinearities + state update ----
    float hv[4];
    #pragma unroll
    for (int r = 0; r < 4; ++r){
      float ig = sigmf(a0[r] + bsv[0][r]);
      float fg = sigmf(a1[r] + bsv[1][r]);
      float gv = tanhfast(a2[r] + bsv[2][r]);
      float og = sigmf(a3[r] + bsv[3][r]);
      float cn = fg*cc[r] + ig*gv;
      cc[r] = cn;
      hv[r] = og * tanhfast(cn);
    }

    // ---- publish: ONE 16B store (8B h + 4B epoch), no drain, no tag ----
    pub16(ringOwnL + (size_t)slot*SLOTB + prodoff,
          f2bf2(hv[0], hv[1]), f2bf2(hv[2], hv[3]), t+1);

    if (t == NT-1){
      f32x4 ov; ov[0]=hv[0]; ov[1]=hv[1]; ov[2]=hv[2]; ov[3]=hv[3];
      *(f32x4*)(out + ((size_t)l*NB + bloc)*NH + jcol) = ov;
    }
  }
}

__global__ __launch_bounds__(256, 1)
void lstm_pipe(const unsigned char* __restrict__ wf, const unsigned char* __restrict__ xf,
               const float* __restrict__ h0,  const float* __restrict__ c0,
               const float* __restrict__ bih, const float* __restrict__ bhh,
               float* __restrict__ out, int* __restrict__ acks,
               unsigned char* __restrict__ ring)
{
  const int tid  = threadIdx.x;
  const int bid  = blockIdx.x;
  const int l    = bid >> 5;          // 32 blocks per layer
  const int s    = (bid >> 1) & 15;
  const int g    = bid & 1;
  const int lane = tid & 63;
  const int wv   = tid >> 6;

  const unsigned char* wfl = wf + (size_t)(l*16 + s)*65536;
  if (l == 0)
    lstm_run<4,12>(wfl, xf, h0, c0, bih, bhh,
                   out, acks, ring, 0, s, g, wv, lane);
  else
    lstm_run<8,16>(wfl, xf, h0, c0,
                   bih + (size_t)l*(4*NH), bhh + (size_t)l*(4*NH),
                   out, acks, ring, l, s, g, wv, lane);
}

extern "C" void kernel_launch(void* const* d_in, const int* in_sizes, int n_in,
                              void* d_out, int out_size, void* d_ws, size_t ws_size,
                              hipStream_t stream)
{
  (void)in_sizes; (void)n_in; (void)out_size; (void)ws_size;
  const float* x    = (const float*)d_in[0];
  const float* h0   = (const float*)d_in[1];
  const float* c0   = (const float*)d_in[2];
  const float* wih0 = (const float*)d_in[3];
  const float* wih  = (const float*)d_in[4];
  const float* whh  = (const float*)d_in[5];
  const float* bih  = (const float*)d_in[6];
  const float* bhh  = (const float*)d_in[7];

  char* p = (char*)d_ws;
  int* acks = (int*)p;                   p += ((ACK_INTS*4 + 255) & ~255);
  unsigned char* wf = (unsigned char*)p; p += WF_BYTES;
  unsigned char* xf = (unsigned char*)p; p += XF_BYTES;
  unsigned char* ring = (unsigned char*)p;   // 6*2*WV*64KB = 49.2 MB; epoch-checked, no memset

  (void)hipMemsetAsync(acks, 0, ACK_INTS*4, stream);
  hipLaunchKernelGGL(prep_w, dim3(1536), dim3(256), 0, stream, wih0, wih, whh, wf);
  hipLaunchKernelGGL(prep_x, dim3(4096), dim3(256), 0, stream, x, xf);
  hipLaunchKernelGGL(lstm_pipe, dim3(NBLK), dim3(256), 0, stream,
                     wf, xf, h0, c0, bih, bhh,
                     (float*)d_out, acks, ring);
}